// Round 9
// baseline (92.820 us; speedup 1.0000x reference)
//
#include <hip/hip_runtime.h>

// Reprojection residual for bundle adjustment.
// Inputs: observe f32[N_OBS,2], cidx i32[N_OBS], pidx i32[N_OBS],
//         K f32[N_CAMS,3], C f32[N_CAMS,7], P f32[N_PTS,3].
// Output: f32[N_OBS,2].
//
// R9: cross-round model: time ~= 4.5cy per L1-missing 64B line-access/CU
// (R4/R7/R8 all fit). Main kernel is ~6% above that floor; remaining cost
// is the cvt dispatch + graph gap (~6us). Fuse cvt into the persistent
// kernel behind a memset-initialized device-atomic grid barrier (256
// blocks x 80KB LDS -> all co-resident by construction; cap 2/CU).
// Cross-XCD visibility: agent-scope release stores for P16 + threadfence
// before arrive; acquire spin + threadfence after. Also v_rcp_f32 instead
// of IEEE divide (~8 VALU/obs, rel err ~1e-7 vs threshold 6.24).

typedef int      vi4 __attribute__((ext_vector_type(4)));
typedef float    vf4 __attribute__((ext_vector_type(4)));
typedef float    vf2 __attribute__((ext_vector_type(2)));
typedef float    vf3 __attribute__((ext_vector_type(3), aligned(4)));
typedef _Float16 vh4 __attribute__((ext_vector_type(4)));

__device__ __forceinline__ void reproj_one(
    float vx, float vy, float vz,
    vf4 q, vf4 tf, vf2 d,
    float obx, float oby, float* ox, float* oy)
{
    float qx = q.x, qy = q.y, qz = q.z, qw = q.w;
    float tx = tf.x, ty = tf.y, tz = tf.z, f = tf.w;
    float k1 = d.x, k2 = d.y;

    float uvx = qy * vz - qz * vy;
    float uvy = qz * vx - qx * vz;
    float uvz = qx * vy - qy * vx;
    float uuvx = qy * uvz - qz * uvy;
    float uuvy = qz * uvx - qx * uvz;
    float uuvz = qx * uvy - qy * uvx;

    float cpx = vx + 2.0f * (qw * uvx + uuvx) + tx;
    float cpy = vy + 2.0f * (qw * uvy + uuvy) + ty;
    float cpz = vz + 2.0f * (qw * uvz + uuvz) + tz;

    float inv = __builtin_amdgcn_rcpf(cpz);   // v_rcp_f32, ~1e-7 rel err
    float nx = -cpx * inv;
    float ny = -cpy * inv;
    float r  = nx * nx + ny * ny;

    float dist = 1.0f + k1 * r + k2 * r * r;
    float fd   = f * dist;

    *ox = fd * nx - obx;
    *oy = fd * ny - oby;
}

template <bool H>
__device__ __forceinline__ vf3 load_pt(const vh4* __restrict__ P16,
                                       const float* __restrict__ P, int i)
{
    if (H) {
        vh4 h = P16[i];
        vf3 r = { (float)h.x, (float)h.y, (float)h.z };
        return r;
    } else {
        return *(const vf3*)(P + 3 * i);
    }
}

template <bool USE_HALF>
__global__ __launch_bounds__(1024, 4) void fused_kernel(
    const float*  __restrict__ observe,
    const int*    __restrict__ cidx,
    const int*    __restrict__ pidx,
    const float*  __restrict__ K,
    const float*  __restrict__ C,
    const float*  __restrict__ P,
    vh4*          __restrict__ P16,
    unsigned int* __restrict__ bar,
    float*        __restrict__ out,
    int n, int ncams, int npts)
{
    extern __shared__ float lds[];
    vf4* Qs = (vf4*)lds;                    // [ncams] qx,qy,qz,qw
    vf4* Ts = (vf4*)(lds + 4 * ncams);      // [ncams] tx,ty,tz,f
    vf2* Ds = (vf2*)(lds + 8 * ncams);      // [ncams] k1,k2

    // ---- phase A: convert this block's slice of P to fp16 (agent-visible) ----
    if (USE_HALF) {
        int nb  = (int)gridDim.x;
        int ppb = (npts + nb - 1) / nb;
        int lo  = blockIdx.x * ppb;
        int hi  = lo + ppb; if (hi > npts) hi = npts;
        for (int i = lo + (int)threadIdx.x; i < hi; i += 1024) {
            vf3 v = *(const vf3*)(P + 3 * i);
            vh4 h = { (_Float16)v.x, (_Float16)v.y, (_Float16)v.z, (_Float16)0.f };
            unsigned long long bits = __builtin_bit_cast(unsigned long long, h);
            __hip_atomic_store((unsigned long long*)(P16 + i), bits,
                               __ATOMIC_RELAXED, __HIP_MEMORY_SCOPE_AGENT);
        }
    }

    // ---- phase B: cooperative LDS cam fill (independent of phase A) ----
    for (int c = threadIdx.x; c < ncams; c += 1024) {
        const float* Cc = C + 7 * c;
        const float* Kc = K + 3 * c;
        vf4 q  = { Cc[3], Cc[4], Cc[5], Cc[6] };
        vf4 tf = { Cc[0], Cc[1], Cc[2], Kc[0] };
        vf2 d  = { Kc[1], Kc[2] };
        Qs[c] = q; Ts[c] = tf; Ds[c] = d;
    }
    __syncthreads();

    // ---- phase C: grid barrier (all gridDim.x blocks co-resident) ----
    if (USE_HALF) {
        if (threadIdx.x == 0) {
            __threadfence();  // release: drain/flush my P16 writes agent-wide
            __hip_atomic_fetch_add(bar, 1u, __ATOMIC_ACQ_REL,
                                   __HIP_MEMORY_SCOPE_AGENT);
            unsigned int nb = gridDim.x;
            while (__hip_atomic_load(bar, __ATOMIC_ACQUIRE,
                                     __HIP_MEMORY_SCOPE_AGENT) < nb)
                __builtin_amdgcn_s_sleep(2);
            __threadfence();  // acquire: invalidate stale L1/L2 lines
        }
        __syncthreads();
    }

    // ---- phase D: persistent pipelined reprojection (R8 structure) ----
    const int stride = gridDim.x * 1024 * 4;
    int base = (blockIdx.x * 1024 + threadIdx.x) * 4;
    if (base >= n) return;
    if (base + 4 > n) {
        for (int i = base; i < n; ++i) {
            int c = cidx[i];
            vf3 pv = load_pt<USE_HALF>(P16, P, pidx[i]);
            float ox, oy;
            reproj_one(pv.x, pv.y, pv.z, Qs[c], Ts[c], Ds[c],
                       observe[2 * i], observe[2 * i + 1], &ox, &oy);
            out[2 * i] = ox; out[2 * i + 1] = oy;
        }
        return;
    }

    // prologue: batch A fully loaded + gathers issued
    vi4 cA = __builtin_nontemporal_load((const vi4*)(cidx + base));
    vi4 pA = __builtin_nontemporal_load((const vi4*)(pidx + base));
    vf4 obA0 = __builtin_nontemporal_load((const vf4*)(observe + 2 * base));
    vf4 obA1 = __builtin_nontemporal_load((const vf4*)(observe + 2 * base + 4));
    vf3 hA0 = load_pt<USE_HALF>(P16, P, pA.x);
    vf3 hA1 = load_pt<USE_HALF>(P16, P, pA.y);
    vf3 hA2 = load_pt<USE_HALF>(P16, P, pA.z);
    vf3 hA3 = load_pt<USE_HALF>(P16, P, pA.w);

    for (;;) {
        int next = base + stride;
        bool have_next = (next + 4 <= n);

        // stage 1: issue next batch's streaming loads
        vi4 cB, pB; vf4 obB0, obB1;
        if (have_next) {
            cB   = __builtin_nontemporal_load((const vi4*)(cidx + next));
            pB   = __builtin_nontemporal_load((const vi4*)(pidx + next));
            obB0 = __builtin_nontemporal_load((const vf4*)(observe + 2 * next));
            obB1 = __builtin_nontemporal_load((const vf4*)(observe + 2 * next + 4));
        }

        // stage 2: compute current batch (gathers issued last iteration)
        float r0, r1, r2, r3, r4, r5, r6, r7;
        reproj_one(hA0.x, hA0.y, hA0.z, Qs[cA.x], Ts[cA.x], Ds[cA.x],
                   obA0.x, obA0.y, &r0, &r1);
        reproj_one(hA1.x, hA1.y, hA1.z, Qs[cA.y], Ts[cA.y], Ds[cA.y],
                   obA0.z, obA0.w, &r2, &r3);
        reproj_one(hA2.x, hA2.y, hA2.z, Qs[cA.z], Ts[cA.z], Ds[cA.z],
                   obA1.x, obA1.y, &r4, &r5);
        reproj_one(hA3.x, hA3.y, hA3.z, Qs[cA.w], Ts[cA.w], Ds[cA.w],
                   obA1.z, obA1.w, &r6, &r7);

        vf4 o0 = { r0, r1, r2, r3 };
        vf4 o1 = { r4, r5, r6, r7 };
        __builtin_nontemporal_store(o0, (vf4*)(out + 2 * base));
        __builtin_nontemporal_store(o1, (vf4*)(out + 2 * base + 4));

        if (!have_next) break;

        // stage 3: rotate and issue next gathers
        cA = cB; obA0 = obB0; obA1 = obB1;
        hA0 = load_pt<USE_HALF>(P16, P, pB.x);
        hA1 = load_pt<USE_HALF>(P16, P, pB.y);
        hA2 = load_pt<USE_HALF>(P16, P, pB.z);
        hA3 = load_pt<USE_HALF>(P16, P, pB.w);
        base = next;
    }
}

extern "C" void kernel_launch(void* const* d_in, const int* in_sizes, int n_in,
                              void* d_out, int out_size, void* d_ws, size_t ws_size,
                              hipStream_t stream)
{
    const float* observe = (const float*)d_in[0];
    const int*   cidx    = (const int*)d_in[1];
    const int*   pidx    = (const int*)d_in[2];
    const float* K       = (const float*)d_in[3];
    const float* C       = (const float*)d_in[4];
    const float* P       = (const float*)d_in[5];
    float*       out     = (float*)d_out;

    int n     = in_sizes[1];          // N_OBS
    int ncams = in_sizes[3] / 3;      // K is [N_CAMS, 3]
    int npts  = in_sizes[5] / 3;      // P is [N_PTS, 3]

    size_t p16_bytes = (size_t)npts * 8;
    size_t bar_off   = (p16_bytes + 255) & ~(size_t)255;
    bool use_half    = (ws_size >= bar_off + 256);

    vh4*          P16 = (vh4*)d_ws;
    unsigned int* bar = (unsigned int*)((char*)d_ws + bar_off);

    int block = 1024;
    int grid  = 256;                  // 1 block/CU; all co-resident (cap 2/CU)
    int need  = (n + block * 4 - 1) / (block * 4);
    if (grid > need) grid = need;
    size_t lds_bytes = (size_t)ncams * 10 * sizeof(float);   // 80,000 B

    if (use_half) {
        hipMemsetAsync(bar, 0, sizeof(unsigned int), stream);
        fused_kernel<true><<<grid, block, lds_bytes, stream>>>(
            observe, cidx, pidx, K, C, P, P16, bar, out, n, ncams, npts);
    } else {
        fused_kernel<false><<<grid, block, lds_bytes, stream>>>(
            observe, cidx, pidx, K, C, P, P16, bar, out, n, ncams, npts);
    }
}

// Round 10
// 61.708 us; speedup vs baseline: 1.5042x; 1.5042x over previous
//
#include <hip/hip_runtime.h>

// Reprojection residual for bundle adjustment.
// Inputs (setup_inputs order):
//   d_in[0] observe : float32 [N_OBS, 2]
//   d_in[1] cidx    : int32   [N_OBS]
//   d_in[2] pidx    : int32   [N_OBS]
//   d_in[3] K       : float32 [N_CAMS, 3]   (focal, k1, k2)
//   d_in[4] C       : float32 [N_CAMS, 7]   (t.xyz, q.xyzw)
//   d_in[5] P       : float32 [N_PTS, 3]
// Output: float32 [N_OBS, 2]
//
// R10: exact R8 revert (61.5us proven: persistent 256-block main kernel,
// fp16 P table in d_ws via separate cvt kernel, cams in 80KB LDS, 2-stage
// software pipeline) + v_rcp_f32 instead of IEEE divide (~8 VALU/obs).
// R9's in-kernel fusion regressed 1.6x: agent-scope atomic stores + acquire
// fence defeated per-XCD L2 residency of P16 (L3 hits invisible in
// FETCH_SIZE). Kernel boundary is the cheap fence - keep two dispatches.
// Cross-round model: time ~= 4.5cy per L1-missing 64B line/CU -> ~51us
// structural floor for the main kernel; this round targets the VALU trim.

typedef int      vi4 __attribute__((ext_vector_type(4)));
typedef float    vf4 __attribute__((ext_vector_type(4)));
typedef float    vf2 __attribute__((ext_vector_type(2)));
typedef float    vf3 __attribute__((ext_vector_type(3), aligned(4)));
typedef _Float16 vh4 __attribute__((ext_vector_type(4)));

// ---- kernel 1: P fp32 -> half4 (8B records) in workspace ----
__global__ __launch_bounds__(1024) void cvt_p_kernel(
    const float* __restrict__ P, vh4* __restrict__ P16, int npts)
{
    int i4 = (blockIdx.x * 1024 + threadIdx.x) * 4;   // 4 points per thread
    if (i4 + 4 <= npts) {
        vf4 a = *(const vf4*)(P + 3 * i4);
        vf4 b = *(const vf4*)(P + 3 * i4 + 4);
        vf4 c = *(const vf4*)(P + 3 * i4 + 8);
        vh4 h0 = { (_Float16)a.x, (_Float16)a.y, (_Float16)a.z, (_Float16)0.f };
        vh4 h1 = { (_Float16)a.w, (_Float16)b.x, (_Float16)b.y, (_Float16)0.f };
        vh4 h2 = { (_Float16)b.z, (_Float16)b.w, (_Float16)c.x, (_Float16)0.f };
        vh4 h3 = { (_Float16)c.y, (_Float16)c.z, (_Float16)c.w, (_Float16)0.f };
        P16[i4 + 0] = h0; P16[i4 + 1] = h1; P16[i4 + 2] = h2; P16[i4 + 3] = h3;
    } else {
        for (int i = i4; i < npts; ++i) {
            vh4 h = { (_Float16)P[3 * i], (_Float16)P[3 * i + 1],
                      (_Float16)P[3 * i + 2], (_Float16)0.f };
            P16[i] = h;
        }
    }
}

__device__ __forceinline__ void reproj_one(
    float vx, float vy, float vz,
    vf4 q, vf4 tf, vf2 d,
    float obx, float oby, float* ox, float* oy)
{
    float qx = q.x, qy = q.y, qz = q.z, qw = q.w;
    float tx = tf.x, ty = tf.y, tz = tf.z, f = tf.w;
    float k1 = d.x, k2 = d.y;

    // uv = cross(qv, v)
    float uvx = qy * vz - qz * vy;
    float uvy = qz * vx - qx * vz;
    float uvz = qx * vy - qy * vx;
    // uuv = cross(qv, uv)
    float uuvx = qy * uvz - qz * uvy;
    float uuvy = qz * uvx - qx * uvz;
    float uuvz = qx * uvy - qy * uvx;

    float cpx = vx + 2.0f * (qw * uvx + uuvx) + tx;
    float cpy = vy + 2.0f * (qw * uvy + uuvy) + ty;
    float cpz = vz + 2.0f * (qw * uvz + uuvz) + tz;

    float inv = __builtin_amdgcn_rcpf(cpz);   // v_rcp_f32, ~1e-7 rel err
    float nx = -cpx * inv;
    float ny = -cpy * inv;
    float r  = nx * nx + ny * ny;

    float dist = 1.0f + k1 * r + k2 * r * r;
    float fd   = f * dist;

    *ox = fd * nx - obx;
    *oy = fd * ny - oby;
}

__global__ __launch_bounds__(1024, 4) void reproj_kernel(
    const float*  __restrict__ observe,
    const int*    __restrict__ cidx,
    const int*    __restrict__ pidx,
    const float*  __restrict__ K,
    const float*  __restrict__ C,
    const vh4*    __restrict__ P16,
    float*        __restrict__ out,
    int n, int ncams)
{
    extern __shared__ float lds[];
    vf4* Qs = (vf4*)lds;                    // [ncams] qx,qy,qz,qw
    vf4* Ts = (vf4*)(lds + 4 * ncams);      // [ncams] tx,ty,tz,f
    vf2* Ds = (vf2*)(lds + 8 * ncams);      // [ncams] k1,k2

    // cooperative LDS fill (ONCE per persistent block): 10 floats/cam = 80,000 B
    for (int c = threadIdx.x; c < ncams; c += 1024) {
        const float* Cc = C + 7 * c;
        const float* Kc = K + 3 * c;
        vf4 q  = { Cc[3], Cc[4], Cc[5], Cc[6] };
        vf4 tf = { Cc[0], Cc[1], Cc[2], Kc[0] };
        vf2 d  = { Kc[1], Kc[2] };
        Qs[c] = q; Ts[c] = tf; Ds[c] = d;
    }
    __syncthreads();

    const int stride = gridDim.x * 1024 * 4;
    int base = (blockIdx.x * 1024 + threadIdx.x) * 4;
    if (base >= n) return;
    if (base + 4 > n) {
        for (int i = base; i < n; ++i) {
            int c = cidx[i];
            vh4 h = P16[pidx[i]];
            float ox, oy;
            reproj_one((float)h.x, (float)h.y, (float)h.z, Qs[c], Ts[c], Ds[c],
                       observe[2 * i], observe[2 * i + 1], &ox, &oy);
            out[2 * i] = ox; out[2 * i + 1] = oy;
        }
        return;
    }

    // ---- prologue: batch A fully loaded + gathers issued ----
    vi4 cA = __builtin_nontemporal_load((const vi4*)(cidx + base));
    vi4 pA = __builtin_nontemporal_load((const vi4*)(pidx + base));
    vf4 obA0 = __builtin_nontemporal_load((const vf4*)(observe + 2 * base));
    vf4 obA1 = __builtin_nontemporal_load((const vf4*)(observe + 2 * base + 4));
    vh4 hA0 = P16[pA.x];
    vh4 hA1 = P16[pA.y];
    vh4 hA2 = P16[pA.z];
    vh4 hA3 = P16[pA.w];

    for (;;) {
        int next = base + stride;
        bool have_next = (next + 4 <= n);

        // stage 1: issue next batch's streaming loads (independent)
        vi4 cB, pB; vf4 obB0, obB1;
        if (have_next) {
            cB   = __builtin_nontemporal_load((const vi4*)(cidx + next));
            pB   = __builtin_nontemporal_load((const vi4*)(pidx + next));
            obB0 = __builtin_nontemporal_load((const vf4*)(observe + 2 * next));
            obB1 = __builtin_nontemporal_load((const vf4*)(observe + 2 * next + 4));
        }

        // stage 2: compute current batch (gathers hA* issued last iteration)
        float r0, r1, r2, r3, r4, r5, r6, r7;
        reproj_one((float)hA0.x, (float)hA0.y, (float)hA0.z,
                   Qs[cA.x], Ts[cA.x], Ds[cA.x], obA0.x, obA0.y, &r0, &r1);
        reproj_one((float)hA1.x, (float)hA1.y, (float)hA1.z,
                   Qs[cA.y], Ts[cA.y], Ds[cA.y], obA0.z, obA0.w, &r2, &r3);
        reproj_one((float)hA2.x, (float)hA2.y, (float)hA2.z,
                   Qs[cA.z], Ts[cA.z], Ds[cA.z], obA1.x, obA1.y, &r4, &r5);
        reproj_one((float)hA3.x, (float)hA3.y, (float)hA3.z,
                   Qs[cA.w], Ts[cA.w], Ds[cA.w], obA1.z, obA1.w, &r6, &r7);

        vf4 o0 = { r0, r1, r2, r3 };
        vf4 o1 = { r4, r5, r6, r7 };
        __builtin_nontemporal_store(o0, (vf4*)(out + 2 * base));
        __builtin_nontemporal_store(o1, (vf4*)(out + 2 * base + 4));

        if (!have_next) break;

        // stage 3: rotate and issue next gathers
        cA = cB; obA0 = obB0; obA1 = obB1;
        hA0 = P16[pB.x];
        hA1 = P16[pB.y];
        hA2 = P16[pB.z];
        hA3 = P16[pB.w];
        base = next;
    }
}

extern "C" void kernel_launch(void* const* d_in, const int* in_sizes, int n_in,
                              void* d_out, int out_size, void* d_ws, size_t ws_size,
                              hipStream_t stream)
{
    const float* observe = (const float*)d_in[0];
    const int*   cidx    = (const int*)d_in[1];
    const int*   pidx    = (const int*)d_in[2];
    const float* K       = (const float*)d_in[3];
    const float* C       = (const float*)d_in[4];
    const float* P       = (const float*)d_in[5];
    float*       out     = (float*)d_out;

    int n     = in_sizes[1];          // N_OBS
    int ncams = in_sizes[3] / 3;      // K is [N_CAMS, 3]
    int npts  = in_sizes[5] / 3;      // P is [N_PTS, 3]

    vh4* P16 = (vh4*)d_ws;            // ws_size (>= 4 MB) holds half4 points

    // convert P to fp16 (L2-resident 4 MB table)
    int cthreads = (npts + 3) / 4;
    int cgrid = (cthreads + 1023) / 1024;
    cvt_p_kernel<<<cgrid, 1024, 0, stream>>>(P, P16, npts);

    // persistent main kernel: 1 block/CU
    int block = 1024;
    int grid  = 256;
    int need  = (n + block * 4 - 1) / (block * 4);
    if (grid > need) grid = need;
    size_t lds_bytes = (size_t)ncams * 10 * sizeof(float);   // 80,000 B

    reproj_kernel<<<grid, block, lds_bytes, stream>>>(
        observe, cidx, pidx, K, C, P16, out, n, ncams);
}